// Round 1
// baseline (971.314 us; speedup 1.0000x reference)
//
#include <hip/hip_runtime.h>
#include <math.h>

#define N_NODES 50000
#define N_EDGES 800000
#define H 128
#define EIN 257
#define EPB 64   // edges per block

typedef short bf16x8 __attribute__((ext_vector_type(8)));
typedef short bf16x4 __attribute__((ext_vector_type(4)));
typedef short bf16x2 __attribute__((ext_vector_type(2)));
typedef float f32x4 __attribute__((ext_vector_type(4)));

// round-to-nearest-even f32 -> bf16 (one-time prep conversions)
static __device__ __forceinline__ short f2bf(float x) {
    unsigned u = __builtin_bit_cast(unsigned, x);
    unsigned r = (u + 0x7FFFu + ((u >> 16) & 1u)) >> 16;
    return (short)r;
}

// cheap round-half-up f32 -> bf16 (2 VALU insts)
static __device__ __forceinline__ short f2bfr(float x) {
    return (short)((__builtin_bit_cast(unsigned, x) + 0x8000u) >> 16);
}

// fast silu
static __device__ __forceinline__ float silu(float x) {
#if __has_builtin(__builtin_amdgcn_rcpf)
    return x * __builtin_amdgcn_rcpf(1.0f + __expf(-x));
#else
    return x / (1.0f + __expf(-x));
#endif
}

// packed bf16 atomic add
static __device__ __forceinline__ void pk_agg_add(unsigned* addr, unsigned val) {
#if __has_builtin(__builtin_amdgcn_global_atomic_fadd_v2bf16)
    bf16x2 v = __builtin_bit_cast(bf16x2, val);
    (void)__builtin_amdgcn_global_atomic_fadd_v2bf16(
        (__attribute__((address_space(1))) bf16x2*)(unsigned long long)addr, v);
#else
    asm volatile("global_atomic_pk_add_bf16 %0, %1, off"
                 :: "v"(addr), "v"(val) : "memory");
#endif
}

// ---- prep: h->bf16, weights->bf16 (padded), agg zero, pos copy ----
#define P_W1  (128*264)
#define P_W2  (128*128)
#define P_TOT (P_W1 + P_W2 + P_W2 + P_W1 + P_W2)
#define NH4   (N_NODES * H / 4)          // h float4 count = 1,600,000
#define AGG16 (N_NODES * H * 2 / 16)     // agg bf16 bytes / 16 = 800,000
#define POS4  ((N_NODES * 3 + 3) / 4)    // pos float4 count (150000/4=37500)

__global__ __launch_bounds__(256) void prep_all(
    const float* __restrict__ hf,
    const float* __restrict__ We1, const float* __restrict__ We2,
    const float* __restrict__ Wc1, const float* __restrict__ Wn1,
    const float* __restrict__ Wn2,
    short* __restrict__ hbf,
    short* __restrict__ W1b, short* __restrict__ W2b, short* __restrict__ Wc1b,
    short* __restrict__ Wn1b, short* __restrict__ Wn2b,
    uint4* __restrict__ aggz, int aggz_n,          // zero-fill region (16B units)
    float4* __restrict__ pos_dst, const float4* __restrict__ pos_src)
{
    int i = blockIdx.x * 256 + threadIdx.x;
    if (i < NH4) {
        float4 v = ((const float4*)hf)[i];
        bf16x4 s4 = { f2bf(v.x), f2bf(v.y), f2bf(v.z), f2bf(v.w) };
        *(bf16x4*)&hbf[i * 4] = s4;
        return;
    }
    i -= NH4;
    if (i < P_TOT) {
        if (i < P_W1) {
            int j = i / 264, k = i % 264;
            W1b[i] = (k < EIN) ? f2bf(We1[j * EIN + k]) : (short)0;
        } else if (i < P_W1 + P_W2) {
            int t = i - P_W1;
            W2b[t] = f2bf(We2[t]);
        } else if (i < P_W1 + 2 * P_W2) {
            int t = i - P_W1 - P_W2;
            Wc1b[t] = f2bf(Wc1[t]);
        } else if (i < P_W1 + 2 * P_W2 + P_W1) {
            int t = i - P_W1 - 2 * P_W2;
            int j = t / 264, k = t % 264;
            Wn1b[t] = (k < 256) ? f2bf(Wn1[j * 256 + k]) : (short)0;
        } else {
            int t = i - 2 * P_W1 - 2 * P_W2;
            Wn2b[t] = f2bf(Wn2[t]);
        }
        return;
    }
    i -= P_TOT;
    if (i < aggz_n) {                    // bf16 +0.0 == 0x0000
        aggz[i] = uint4{0u, 0u, 0u, 0u};
        return;
    }
    i -= aggz_n;
    if (i < POS4) pos_dst[i] = pos_src[i];
}

// ---- edge kernel: 64 edges / block, 256 threads (4 waves) ----
// GEMMs are operand-SWAPPED: a-frag = weight rows (channels), b-frag = edge rows.
// D layout then has channel on the q*4+r axis and edge on the l15 axis, so each
// lane holds 4 CONSECUTIVE channels of one edge -> packed ds_write_b64 epilogues
// and an 8-shuffle dot reduce. Agg atomics issue after the last barrier
// (fire-and-forget, never drained by a vmcnt(0)).
template<bool AGGBF16>
__global__ __launch_bounds__(256, 4) void edge_kernel(
    const short* __restrict__ hbf, const float* __restrict__ pos,
    const int* __restrict__ eidx,
    const float* __restrict__ We1f, const float* __restrict__ be1,
    const float* __restrict__ be2, const float* __restrict__ bc1,
    const float* __restrict__ wc2f, const float* __restrict__ bc2,
    const short* __restrict__ W1b, const short* __restrict__ W2b,
    const short* __restrict__ Wc1b,
    unsigned* __restrict__ aggb,   // bf16 agg, 64 dwords/row
    float* __restrict__ aggf,      // f32 agg (fallback)
    float* __restrict__ pos_out)
{
    __shared__ union {
        short ein[EPB][264];                               // 33792 B (phase A)
        struct { short t[EPB][136]; short m[EPB][136]; } p; // 34816 B (phase B)
    } s_u;
    __shared__ float s_rn[EPB];
    __shared__ float s_unit[EPB][3];
    __shared__ int   s_row[EPB];
    __shared__ float s_dot[EPB];

    const int tid = threadIdx.x;
    const int eb  = blockIdx.x * EPB;

    if (tid < EPB) {
        int ge = eb + tid;
        int r = eidx[ge];
        int c = eidx[N_EDGES + ge];
        s_row[tid] = r;
        float dx = pos[r*3+0] - pos[c*3+0];
        float dy = pos[r*3+1] - pos[c*3+1];
        float dz = pos[r*3+2] - pos[c*3+2];
        float nrm = sqrtf(dx*dx + dy*dy + dz*dz);
        float rn  = fmaxf(nrm, 1e-8f);
        s_rn[tid] = rn;
        s_unit[tid][0] = dx / rn;
        s_unit[tid][1] = dy / rn;
        s_unit[tid][2] = dz / rn;
        s_dot[tid] = 0.0f;
    }

    // gather hbf[row]|hbf[col] -> s_ein: pure bf16 16B moves.
    {
        const int rlane = tid & 15;
        const int row0  = tid >> 4;      // 0..15
        int idxs[8];
        #pragma unroll
        for (int it = 0; it < 8; ++it) {
            int rr = row0 + it * 16;     // 0..127
            int e  = rr & 63, sg = rr >> 6;
            idxs[it] = eidx[(sg ? N_EDGES : 0) + eb + e];
        }
        #pragma unroll
        for (int it = 0; it < 8; ++it) {
            int rr = row0 + it * 16;
            int e  = rr & 63, sg = rr >> 6;
            bf16x8 v = *(const bf16x8*)&hbf[(size_t)idxs[it] * H + rlane * 8];
            *(bf16x8*)&s_u.ein[e][sg * 128 + rlane * 8] = v;
        }
    }
    __syncthreads();   // barrier 1: ein ready

    const int lane = tid & 63;
    const int q    = lane >> 4;
    const int l15  = lane & 15;
    const int n0   = (tid >> 6) * 32;    // wave's channel base
    const int w    = tid >> 6;

    // ---------------- GEMM1 (swapped): We1 @ ein^T ----------------
    f32x4 acc[2][4] = {};   // [channel-tile ct][edge-tile et]
    __builtin_amdgcn_s_setprio(1);
    #pragma unroll
    for (int ks = 0; ks < 8; ++ks) {
        int k0 = ks * 32 + q * 8;
        bf16x8 w0 = *(const bf16x8*)&W1b[(n0 + l15) * 264 + k0];
        bf16x8 w1 = *(const bf16x8*)&W1b[(n0 + 16 + l15) * 264 + k0];
        bf16x8 e0 = *(const bf16x8*)&s_u.ein[l15][k0];
        bf16x8 e1 = *(const bf16x8*)&s_u.ein[16 + l15][k0];
        bf16x8 e2 = *(const bf16x8*)&s_u.ein[32 + l15][k0];
        bf16x8 e3 = *(const bf16x8*)&s_u.ein[48 + l15][k0];
        acc[0][0] = __builtin_amdgcn_mfma_f32_16x16x32_bf16(w0, e0, acc[0][0], 0, 0, 0);
        acc[0][1] = __builtin_amdgcn_mfma_f32_16x16x32_bf16(w0, e1, acc[0][1], 0, 0, 0);
        acc[0][2] = __builtin_amdgcn_mfma_f32_16x16x32_bf16(w0, e2, acc[0][2], 0, 0, 0);
        acc[0][3] = __builtin_amdgcn_mfma_f32_16x16x32_bf16(w0, e3, acc[0][3], 0, 0, 0);
        acc[1][0] = __builtin_amdgcn_mfma_f32_16x16x32_bf16(w1, e0, acc[1][0], 0, 0, 0);
        acc[1][1] = __builtin_amdgcn_mfma_f32_16x16x32_bf16(w1, e1, acc[1][1], 0, 0, 0);
        acc[1][2] = __builtin_amdgcn_mfma_f32_16x16x32_bf16(w1, e2, acc[1][2], 0, 0, 0);
        acc[1][3] = __builtin_amdgcn_mfma_f32_16x16x32_bf16(w1, e3, acc[1][3], 0, 0, 0);
    }
    __builtin_amdgcn_s_setprio(0);

    // epilogue 1 into registers (ein still live until barrier 2)
    float w256v[2][4], b1v[2][4], rn_e[4];
    #pragma unroll
    for (int ct = 0; ct < 2; ++ct)
        #pragma unroll
        for (int r = 0; r < 4; ++r) {
            int ch = n0 + ct * 16 + q * 4 + r;
            w256v[ct][r] = We1f[ch * EIN + 256];   // rank-1 fixup for odd K
            b1v[ct][r]   = be1[ch];
        }
    #pragma unroll
    for (int et = 0; et < 4; ++et) rn_e[et] = s_rn[et * 16 + l15];

    bf16x4 tv[2][4];
    #pragma unroll
    for (int ct = 0; ct < 2; ++ct)
        #pragma unroll
        for (int et = 0; et < 4; ++et) {
            bf16x4 v;
            #pragma unroll
            for (int r = 0; r < 4; ++r)
                v[r] = f2bfr(silu(acc[ct][et][r] + rn_e[et] * w256v[ct][r] + b1v[ct][r]));
            tv[ct][et] = v;
        }
    __syncthreads();   // barrier 2: all MFMA reads of ein done -> t may overlay
    #pragma unroll
    for (int ct = 0; ct < 2; ++ct)
        #pragma unroll
        for (int et = 0; et < 4; ++et)
            *(bf16x4*)&s_u.p.t[et * 16 + l15][n0 + ct * 16 + q * 4] = tv[ct][et];
    __syncthreads();   // barrier 3: t ready

    // ---------------- GEMM2 (swapped): We2 @ t^T -> m ----------------
    f32x4 acc2[2][4] = {};
    __builtin_amdgcn_s_setprio(1);
    #pragma unroll
    for (int ks = 0; ks < 4; ++ks) {
        int k0 = ks * 32 + q * 8;
        bf16x8 w0 = *(const bf16x8*)&W2b[(n0 + l15) * 128 + k0];
        bf16x8 w1 = *(const bf16x8*)&W2b[(n0 + 16 + l15) * 128 + k0];
        bf16x8 e0 = *(const bf16x8*)&s_u.p.t[l15][k0];
        bf16x8 e1 = *(const bf16x8*)&s_u.p.t[16 + l15][k0];
        bf16x8 e2 = *(const bf16x8*)&s_u.p.t[32 + l15][k0];
        bf16x8 e3 = *(const bf16x8*)&s_u.p.t[48 + l15][k0];
        acc2[0][0] = __builtin_amdgcn_mfma_f32_16x16x32_bf16(w0, e0, acc2[0][0], 0, 0, 0);
        acc2[0][1] = __builtin_amdgcn_mfma_f32_16x16x32_bf16(w0, e1, acc2[0][1], 0, 0, 0);
        acc2[0][2] = __builtin_amdgcn_mfma_f32_16x16x32_bf16(w0, e2, acc2[0][2], 0, 0, 0);
        acc2[0][3] = __builtin_amdgcn_mfma_f32_16x16x32_bf16(w0, e3, acc2[0][3], 0, 0, 0);
        acc2[1][0] = __builtin_amdgcn_mfma_f32_16x16x32_bf16(w1, e0, acc2[1][0], 0, 0, 0);
        acc2[1][1] = __builtin_amdgcn_mfma_f32_16x16x32_bf16(w1, e1, acc2[1][1], 0, 0, 0);
        acc2[1][2] = __builtin_amdgcn_mfma_f32_16x16x32_bf16(w1, e2, acc2[1][2], 0, 0, 0);
        acc2[1][3] = __builtin_amdgcn_mfma_f32_16x16x32_bf16(w1, e3, acc2[1][3], 0, 0, 0);
    }
    __builtin_amdgcn_s_setprio(0);

    // epilogue 2 writes m region (disjoint from t region; no barrier needed)
    {
        float b2v[2][4];
        #pragma unroll
        for (int ct = 0; ct < 2; ++ct)
            #pragma unroll
            for (int r = 0; r < 4; ++r)
                b2v[ct][r] = be2[n0 + ct * 16 + q * 4 + r];
        #pragma unroll
        for (int ct = 0; ct < 2; ++ct)
            #pragma unroll
            for (int et = 0; et < 4; ++et) {
                bf16x4 v;
                #pragma unroll
                for (int r = 0; r < 4; ++r)
                    v[r] = f2bfr(acc2[ct][et][r] + b2v[ct][r]);
                *(bf16x4*)&s_u.p.m[et * 16 + l15][n0 + ct * 16 + q * 4] = v;
            }
    }
    __syncthreads();   // barrier 4: m ready

    // ---------------- GEMM3 (swapped): Wc1 @ m^T, dot wc2 ----------------
    f32x4 acc3[2][4] = {};
    __builtin_amdgcn_s_setprio(1);
    #pragma unroll
    for (int ks = 0; ks < 4; ++ks) {
        int k0 = ks * 32 + q * 8;
        bf16x8 w0 = *(const bf16x8*)&Wc1b[(n0 + l15) * 128 + k0];
        bf16x8 w1 = *(const bf16x8*)&Wc1b[(n0 + 16 + l15) * 128 + k0];
        bf16x8 e0 = *(const bf16x8*)&s_u.p.m[l15][k0];
        bf16x8 e1 = *(const bf16x8*)&s_u.p.m[16 + l15][k0];
        bf16x8 e2 = *(const bf16x8*)&s_u.p.m[32 + l15][k0];
        bf16x8 e3 = *(const bf16x8*)&s_u.p.m[48 + l15][k0];
        acc3[0][0] = __builtin_amdgcn_mfma_f32_16x16x32_bf16(w0, e0, acc3[0][0], 0, 0, 0);
        acc3[0][1] = __builtin_amdgcn_mfma_f32_16x16x32_bf16(w0, e1, acc3[0][1], 0, 0, 0);
        acc3[0][2] = __builtin_amdgcn_mfma_f32_16x16x32_bf16(w0, e2, acc3[0][2], 0, 0, 0);
        acc3[0][3] = __builtin_amdgcn_mfma_f32_16x16x32_bf16(w0, e3, acc3[0][3], 0, 0, 0);
        acc3[1][0] = __builtin_amdgcn_mfma_f32_16x16x32_bf16(w1, e0, acc3[1][0], 0, 0, 0);
        acc3[1][1] = __builtin_amdgcn_mfma_f32_16x16x32_bf16(w1, e1, acc3[1][1], 0, 0, 0);
        acc3[1][2] = __builtin_amdgcn_mfma_f32_16x16x32_bf16(w1, e2, acc3[1][2], 0, 0, 0);
        acc3[1][3] = __builtin_amdgcn_mfma_f32_16x16x32_bf16(w1, e3, acc3[1][3], 0, 0, 0);
    }
    __builtin_amdgcn_s_setprio(0);

    // per-lane partial dot over this lane's 8 channels, per edge tile
    float p[4] = {0.f, 0.f, 0.f, 0.f};
    #pragma unroll
    for (int ct = 0; ct < 2; ++ct)
        #pragma unroll
        for (int r = 0; r < 4; ++r) {
            int ch = n0 + ct * 16 + q * 4 + r;
            float bias = bc1[ch];
            float w2   = wc2f[ch];
            #pragma unroll
            for (int et = 0; et < 4; ++et)
                p[et] += silu(acc3[ct][et][r] + bias) * w2;
        }
    #pragma unroll
    for (int et = 0; et < 4; ++et) {
        float v = p[et];
        v += __shfl_xor(v, 16);
        v += __shfl_xor(v, 32);
        if (q == et) atomicAdd(&s_dot[et * 16 + l15], v);  // one LDS atomic / lane
    }
    __syncthreads();   // barrier 5: s_dot complete

    // ---- tail: pos update + agg atomics (fire-and-forget, never drained) ----
    if (tid < EPB) {
        float s = tanhf(s_dot[tid] + bc2[0]) * 0.1f;
        int r = s_row[tid];
        atomicAdd(&pos_out[r * 3 + 0], s * s_unit[tid][0]);
        atomicAdd(&pos_out[r * 3 + 1], s * s_unit[tid][1]);
        atomicAdd(&pos_out[r * 3 + 2], s * s_unit[tid][2]);
    }

    if constexpr (AGGBF16) {
        const int rg = lane >> 4;              // 0..3
        #pragma unroll
        for (int i = 0; i < 4; ++i) {
            int row = w * 16 + i * 4 + rg;     // wave covers rows w*16..w*16+15
            uint4 pr = *(const uint4*)&s_u.p.m[row][l15 * 8];
            unsigned* dst = &aggb[(size_t)s_row[row] * 64 + l15 * 4];
            pk_agg_add(dst + 0, pr.x);
            pk_agg_add(dst + 1, pr.y);
            pk_agg_add(dst + 2, pr.z);
            pk_agg_add(dst + 3, pr.w);
        }
    } else {
        #pragma unroll
        for (int i = 0; i < 16; ++i) {
            int row = w + i * 4;
            unsigned pr = *(const unsigned*)&s_u.p.m[row][lane * 2];
            float f0 = __builtin_bit_cast(float, pr << 16);
            float f1 = __builtin_bit_cast(float, pr & 0xFFFF0000u);
            float* dst = &aggf[(size_t)s_row[row] * H + 2 * lane];
            atomicAdd(dst, f0);
            atomicAdd(dst + 1, f1);
        }
    }
}

// ---- node kernel: 32 nodes / block ----
template<bool AGGBF16>
__global__ __launch_bounds__(256) void node_kernel(
    const float* __restrict__ h, const short* __restrict__ hbf,
    const unsigned short* __restrict__ aggb, const float* __restrict__ aggf,
    const float* __restrict__ bn1, const float* __restrict__ bn2,
    const short* __restrict__ Wn1b, const short* __restrict__ Wn2b,
    float* __restrict__ hout)
{
    __shared__ short s_a[32][264];
    __shared__ short s_t[32][136];

    const int tid = threadIdx.x;
    const int nb  = blockIdx.x * 32;

    {
        const int rlane = tid & 15;
        const int row0  = tid >> 4;
        #pragma unroll
        for (int it = 0; it < 4; ++it) {
            int rr = row0 + it * 16;     // 0..63
            int e  = rr & 31, sg = rr >> 5;
            int node = nb + e;
            if (node >= N_NODES) node = N_NODES - 1;
            bf16x8 v;
            if (sg == 0) {
                v = *(const bf16x8*)&hbf[(size_t)node * H + rlane * 8];
            } else if constexpr (AGGBF16) {
                v = *(const bf16x8*)&aggb[(size_t)node * H + rlane * 8];
            } else {
                const float* src = &aggf[(size_t)node * H + rlane * 8];
                bf16x8 t;
                #pragma unroll
                for (int j = 0; j < 8; ++j) t[j] = f2bfr(src[j]);
                v = t;
            }
            *(bf16x8*)&s_a[e][sg * 128 + rlane * 8] = v;
        }
    }
    __syncthreads();

    const int lane = tid & 63;
    const int q    = lane >> 4;
    const int l15  = lane & 15;
    const int n0   = (tid >> 6) * 32;

    f32x4 acc[2][2] = {};
    #pragma unroll
    for (int ks = 0; ks < 8; ++ks) {
        int k0 = ks * 32 + q * 8;
        bf16x8 a0 = *(const bf16x8*)&s_a[l15][k0];
        bf16x8 a1 = *(const bf16x8*)&s_a[16 + l15][k0];
        bf16x8 b0 = *(const bf16x8*)&Wn1b[(n0 + l15) * 264 + k0];
        bf16x8 b1 = *(const bf16x8*)&Wn1b[(n0 + 16 + l15) * 264 + k0];
        acc[0][0] = __builtin_amdgcn_mfma_f32_16x16x32_bf16(a0, b0, acc[0][0], 0, 0, 0);
        acc[0][1] = __builtin_amdgcn_mfma_f32_16x16x32_bf16(a0, b1, acc[0][1], 0, 0, 0);
        acc[1][0] = __builtin_amdgcn_mfma_f32_16x16x32_bf16(a1, b0, acc[1][0], 0, 0, 0);
        acc[1][1] = __builtin_amdgcn_mfma_f32_16x16x32_bf16(a1, b1, acc[1][1], 0, 0, 0);
    }
    #pragma unroll
    for (int ct = 0; ct < 2; ++ct) {
        int col = n0 + ct * 16 + l15;
        float bias = bn1[col];
        #pragma unroll
        for (int rt = 0; rt < 2; ++rt) {
            #pragma unroll
            for (int r = 0; r < 4; ++r) {
                int row = rt * 16 + q * 4 + r;
                s_t[row][col] = f2bfr(silu(acc[rt][ct][r] + bias));
            }
        }
    }
    __syncthreads();

    f32x4 acc2[2][2] = {};
    #pragma unroll
    for (int ks = 0; ks < 4; ++ks) {
        int k0 = ks * 32 + q * 8;
        bf16x8 a0 = *(const bf16x8*)&s_t[l15][k0];
        bf16x8 a1 = *(const bf16x8*)&s_t[16 + l15][k0];
        bf16x8 b0 = *(const bf16x8*)&Wn2b[(n0 + l15) * 128 + k0];
        bf16x8 b1 = *(const bf16x8*)&Wn2b[(n0 + 16 + l15) * 128 + k0];
        acc2[0][0] = __builtin_amdgcn_mfma_f32_16x16x32_bf16(a0, b0, acc2[0][0], 0, 0, 0);
        acc2[0][1] = __builtin_amdgcn_mfma_f32_16x16x32_bf16(a0, b1, acc2[0][1], 0, 0, 0);
        acc2[1][0] = __builtin_amdgcn_mfma_f32_16x16x32_bf16(a1, b0, acc2[1][0], 0, 0, 0);
        acc2[1][1] = __builtin_amdgcn_mfma_f32_16x16x32_bf16(a1, b1, acc2[1][1], 0, 0, 0);
    }
    #pragma unroll
    for (int ct = 0; ct < 2; ++ct) {
        int col = n0 + ct * 16 + l15;
        float bias = bn2[col];
        #pragma unroll
        for (int rt = 0; rt < 2; ++rt) {
            #pragma unroll
            for (int r = 0; r < 4; ++r) {
                int row = rt * 16 + q * 4 + r;
                int nrow = nb + row;
                if (nrow < N_NODES) {
                    float v = acc2[rt][ct][r] + bias + h[(size_t)nrow * H + col];
                    hout[(size_t)nrow * H + col] = v;
                }
            }
        }
    }
}

extern "C" void kernel_launch(void* const* d_in, const int* in_sizes, int n_in,
                              void* d_out, int out_size, void* d_ws, size_t ws_size,
                              hipStream_t stream) {
    const float* h   = (const float*)d_in[0];
    const float* pos = (const float*)d_in[1];
    const int*  eidx = (const int*)d_in[2];
    const float* We1 = (const float*)d_in[3];
    const float* be1 = (const float*)d_in[4];
    const float* We2 = (const float*)d_in[5];
    const float* be2 = (const float*)d_in[6];
    const float* Wn1 = (const float*)d_in[7];
    const float* bn1 = (const float*)d_in[8];
    const float* Wn2 = (const float*)d_in[9];
    const float* bn2 = (const float*)d_in[10];
    const float* Wc1 = (const float*)d_in[11];
    const float* bc1 = (const float*)d_in[12];
    const float* Wc2 = (const float*)d_in[13];
    const float* bc2 = (const float*)d_in[14];

    float* out_h   = (float*)d_out;
    float* out_pos = out_h + (size_t)N_NODES * H;

    char* ws = (char*)d_ws;
    short* W1b  = (short*)(ws);
    short* W2b  = (short*)(ws + 2 * P_W1);
    short* Wc1b = (short*)(ws + 2 * (P_W1 + P_W2));
    short* Wn1b = (short*)(ws + 2 * (P_W1 + 2 * P_W2));
    short* Wn2b = (short*)(ws + 2 * (2 * P_W1 + 2 * P_W2));
    const size_t WSW = 2 * (size_t)(2 * P_W1 + 3 * P_W2);   // 233472 B
    const size_t HBF = (size_t)N_NODES * H * 2;             // 12.8 MB
    const size_t AGG = (size_t)N_NODES * H * 2;             // 12.8 MB
    short* hbf = (short*)(ws + WSW);
    const bool use_bf16 = (ws_size >= WSW + HBF + AGG);

    if (use_bf16) {
        unsigned* aggb = (unsigned*)(ws + WSW + HBF);
        const int prep_n = NH4 + P_TOT + AGG16 + POS4;
        prep_all<<<(prep_n + 255) / 256, 256, 0, stream>>>(
            h, We1, We2, Wc1, Wn1, Wn2, hbf, W1b, W2b, Wc1b, Wn1b, Wn2b,
            (uint4*)aggb, AGG16, (float4*)out_pos, (const float4*)pos);
        edge_kernel<true><<<N_EDGES / EPB, 256, 0, stream>>>(
            hbf, pos, eidx, We1, be1, be2, bc1, Wc2, bc2,
            W1b, W2b, Wc1b, aggb, nullptr, out_pos);
        node_kernel<true><<<(N_NODES + 31) / 32, 256, 0, stream>>>(
            h, hbf, (const unsigned short*)aggb, nullptr,
            bn1, bn2, Wn1b, Wn2b, out_h);
    } else {
        // fallback: f32 agg in d_out h region
        const int prep_n = NH4 + P_TOT + POS4;
        prep_all<<<(prep_n + 255) / 256, 256, 0, stream>>>(
            h, We1, We2, Wc1, Wn1, Wn2, hbf, W1b, W2b, Wc1b, Wn1b, Wn2b,
            nullptr, 0, (float4*)out_pos, (const float4*)pos);
        hipMemsetAsync(out_h, 0, (size_t)N_NODES * H * sizeof(float), stream);
        edge_kernel<false><<<N_EDGES / EPB, 256, 0, stream>>>(
            hbf, pos, eidx, We1, be1, be2, bc1, Wc2, bc2,
            W1b, W2b, Wc1b, nullptr, out_h, out_pos);
        node_kernel<false><<<(N_NODES + 31) / 32, 256, 0, stream>>>(
            h, hbf, nullptr, out_h, bn1, bn2, Wn1b, Wn2b, out_h);
    }
}

// Round 2
// 498.052 us; speedup vs baseline: 1.9502x; 1.9502x over previous
//
#include <hip/hip_runtime.h>
#include <math.h>

#define N_NODES 50000
#define N_EDGES 800000
#define H 128
#define EIN 257
#define EPB 64   // edges per block

typedef short bf16x8 __attribute__((ext_vector_type(8)));
typedef short bf16x4 __attribute__((ext_vector_type(4)));
typedef short bf16x2 __attribute__((ext_vector_type(2)));
typedef float f32x4 __attribute__((ext_vector_type(4)));

// round-to-nearest-even f32 -> bf16 (one-time prep conversions)
static __device__ __forceinline__ short f2bf(float x) {
    unsigned u = __builtin_bit_cast(unsigned, x);
    unsigned r = (u + 0x7FFFu + ((u >> 16) & 1u)) >> 16;
    return (short)r;
}

// cheap round-half-up f32 -> bf16 (2 VALU insts)
static __device__ __forceinline__ short f2bfr(float x) {
    return (short)((__builtin_bit_cast(unsigned, x) + 0x8000u) >> 16);
}

// fast silu
static __device__ __forceinline__ float silu(float x) {
#if __has_builtin(__builtin_amdgcn_rcpf)
    return x * __builtin_amdgcn_rcpf(1.0f + __expf(-x));
#else
    return x / (1.0f + __expf(-x));
#endif
}

// packed bf16 atomic add
static __device__ __forceinline__ void pk_agg_add(unsigned* addr, unsigned val) {
#if __has_builtin(__builtin_amdgcn_global_atomic_fadd_v2bf16)
    bf16x2 v = __builtin_bit_cast(bf16x2, val);
    (void)__builtin_amdgcn_global_atomic_fadd_v2bf16(
        (__attribute__((address_space(1))) bf16x2*)(unsigned long long)addr, v);
#else
    asm volatile("global_atomic_pk_add_bf16 %0, %1, off"
                 :: "v"(addr), "v"(val) : "memory");
#endif
}

// ---- prep: h->bf16, weights->bf16 (padded), agg zero, pos copy ----
#define P_W1  (128*264)
#define P_W2  (128*128)
#define P_TOT (P_W1 + P_W2 + P_W2 + P_W1 + P_W2)
#define NH4   (N_NODES * H / 4)          // h float4 count = 1,600,000
#define AGG16 (N_NODES * H * 2 / 16)     // agg bf16 bytes / 16 = 800,000
#define POS4  ((N_NODES * 3 + 3) / 4)    // pos float4 count (150000/4=37500)

__global__ __launch_bounds__(256) void prep_all(
    const float* __restrict__ hf,
    const float* __restrict__ We1, const float* __restrict__ We2,
    const float* __restrict__ Wc1, const float* __restrict__ Wn1,
    const float* __restrict__ Wn2,
    short* __restrict__ hbf,
    short* __restrict__ W1b, short* __restrict__ W2b, short* __restrict__ Wc1b,
    short* __restrict__ Wn1b, short* __restrict__ Wn2b,
    uint4* __restrict__ aggz, int aggz_n,          // zero-fill region (16B units)
    float4* __restrict__ pos_dst, const float4* __restrict__ pos_src)
{
    int i = blockIdx.x * 256 + threadIdx.x;
    if (i < NH4) {
        float4 v = ((const float4*)hf)[i];
        bf16x4 s4 = { f2bf(v.x), f2bf(v.y), f2bf(v.z), f2bf(v.w) };
        *(bf16x4*)&hbf[i * 4] = s4;
        return;
    }
    i -= NH4;
    if (i < P_TOT) {
        if (i < P_W1) {
            int j = i / 264, k = i % 264;
            W1b[i] = (k < EIN) ? f2bf(We1[j * EIN + k]) : (short)0;
        } else if (i < P_W1 + P_W2) {
            int t = i - P_W1;
            W2b[t] = f2bf(We2[t]);
        } else if (i < P_W1 + 2 * P_W2) {
            int t = i - P_W1 - P_W2;
            Wc1b[t] = f2bf(Wc1[t]);
        } else if (i < P_W1 + 2 * P_W2 + P_W1) {
            int t = i - P_W1 - 2 * P_W2;
            int j = t / 264, k = t % 264;
            Wn1b[t] = (k < 256) ? f2bf(Wn1[j * 256 + k]) : (short)0;
        } else {
            int t = i - 2 * P_W1 - 2 * P_W2;
            Wn2b[t] = f2bf(Wn2[t]);
        }
        return;
    }
    i -= P_TOT;
    if (i < aggz_n) {                    // bf16 +0.0 == 0x0000
        aggz[i] = uint4{0u, 0u, 0u, 0u};
        return;
    }
    i -= aggz_n;
    if (i < POS4) pos_dst[i] = pos_src[i];
}

// ---- edge kernel: 64 edges / block, 256 threads (4 waves) ----
// GEMMs are operand-SWAPPED: a-frag = weight rows (channels), b-frag = edge rows.
// D layout then has channel on the q*4+r axis and edge on the l15 axis, so each
// lane holds 4 CONSECUTIVE channels of one edge -> packed ds_write_b64 epilogues
// and an 8-shuffle dot reduce.
// Agg atomics: wave-per-row 64-consecutive-dword bursts (256B contiguous per
// instruction -> fully-written L2 lines; scattered layouts tripled WRITE_SIZE).
// Issued after the last barrier: fire-and-forget, never drained by a vmcnt(0).
template<bool AGGBF16>
__global__ __launch_bounds__(256, 4) void edge_kernel(
    const short* __restrict__ hbf, const float* __restrict__ pos,
    const int* __restrict__ eidx,
    const float* __restrict__ We1f, const float* __restrict__ be1,
    const float* __restrict__ be2, const float* __restrict__ bc1,
    const float* __restrict__ wc2f, const float* __restrict__ bc2,
    const short* __restrict__ W1b, const short* __restrict__ W2b,
    const short* __restrict__ Wc1b,
    unsigned* __restrict__ aggb,   // bf16 agg, 64 dwords/row
    float* __restrict__ aggf,      // f32 agg (fallback)
    float* __restrict__ pos_out)
{
    __shared__ union {
        short ein[EPB][264];                               // 33792 B (phase A)
        struct { short t[EPB][136]; short m[EPB][136]; } p; // 34816 B (phase B)
    } s_u;
    __shared__ float s_rn[EPB];
    __shared__ float s_unit[EPB][3];
    __shared__ int   s_row[EPB];
    __shared__ float s_dot[EPB];

    const int tid = threadIdx.x;
    const int eb  = blockIdx.x * EPB;

    if (tid < EPB) {
        int ge = eb + tid;
        int r = eidx[ge];
        int c = eidx[N_EDGES + ge];
        s_row[tid] = r;
        float dx = pos[r*3+0] - pos[c*3+0];
        float dy = pos[r*3+1] - pos[c*3+1];
        float dz = pos[r*3+2] - pos[c*3+2];
        float nrm = sqrtf(dx*dx + dy*dy + dz*dz);
        float rn  = fmaxf(nrm, 1e-8f);
        s_rn[tid] = rn;
        s_unit[tid][0] = dx / rn;
        s_unit[tid][1] = dy / rn;
        s_unit[tid][2] = dz / rn;
        s_dot[tid] = 0.0f;
    }

    // gather hbf[row]|hbf[col] -> s_ein: pure bf16 16B moves.
    {
        const int rlane = tid & 15;
        const int row0  = tid >> 4;      // 0..15
        int idxs[8];
        #pragma unroll
        for (int it = 0; it < 8; ++it) {
            int rr = row0 + it * 16;     // 0..127
            int e  = rr & 63, sg = rr >> 6;
            idxs[it] = eidx[(sg ? N_EDGES : 0) + eb + e];
        }
        #pragma unroll
        for (int it = 0; it < 8; ++it) {
            int rr = row0 + it * 16;
            int e  = rr & 63, sg = rr >> 6;
            bf16x8 v = *(const bf16x8*)&hbf[(size_t)idxs[it] * H + rlane * 8];
            *(bf16x8*)&s_u.ein[e][sg * 128 + rlane * 8] = v;
        }
    }
    __syncthreads();   // barrier 1: ein ready

    const int lane = tid & 63;
    const int q    = lane >> 4;
    const int l15  = lane & 15;
    const int n0   = (tid >> 6) * 32;    // wave's channel base
    const int w    = tid >> 6;

    // ---------------- GEMM1 (swapped): We1 @ ein^T ----------------
    f32x4 acc[2][4] = {};   // [channel-tile ct][edge-tile et]
    __builtin_amdgcn_s_setprio(1);
    #pragma unroll
    for (int ks = 0; ks < 8; ++ks) {
        int k0 = ks * 32 + q * 8;
        bf16x8 w0 = *(const bf16x8*)&W1b[(n0 + l15) * 264 + k0];
        bf16x8 w1 = *(const bf16x8*)&W1b[(n0 + 16 + l15) * 264 + k0];
        bf16x8 e0 = *(const bf16x8*)&s_u.ein[l15][k0];
        bf16x8 e1 = *(const bf16x8*)&s_u.ein[16 + l15][k0];
        bf16x8 e2 = *(const bf16x8*)&s_u.ein[32 + l15][k0];
        bf16x8 e3 = *(const bf16x8*)&s_u.ein[48 + l15][k0];
        acc[0][0] = __builtin_amdgcn_mfma_f32_16x16x32_bf16(w0, e0, acc[0][0], 0, 0, 0);
        acc[0][1] = __builtin_amdgcn_mfma_f32_16x16x32_bf16(w0, e1, acc[0][1], 0, 0, 0);
        acc[0][2] = __builtin_amdgcn_mfma_f32_16x16x32_bf16(w0, e2, acc[0][2], 0, 0, 0);
        acc[0][3] = __builtin_amdgcn_mfma_f32_16x16x32_bf16(w0, e3, acc[0][3], 0, 0, 0);
        acc[1][0] = __builtin_amdgcn_mfma_f32_16x16x32_bf16(w1, e0, acc[1][0], 0, 0, 0);
        acc[1][1] = __builtin_amdgcn_mfma_f32_16x16x32_bf16(w1, e1, acc[1][1], 0, 0, 0);
        acc[1][2] = __builtin_amdgcn_mfma_f32_16x16x32_bf16(w1, e2, acc[1][2], 0, 0, 0);
        acc[1][3] = __builtin_amdgcn_mfma_f32_16x16x32_bf16(w1, e3, acc[1][3], 0, 0, 0);
    }
    __builtin_amdgcn_s_setprio(0);

    // epilogue 1 into registers (ein still live until barrier 2)
    float w256v[2][4], b1v[2][4], rn_e[4];
    #pragma unroll
    for (int ct = 0; ct < 2; ++ct)
        #pragma unroll
        for (int r = 0; r < 4; ++r) {
            int ch = n0 + ct * 16 + q * 4 + r;
            w256v[ct][r] = We1f[ch * EIN + 256];   // rank-1 fixup for odd K
            b1v[ct][r]   = be1[ch];
        }
    #pragma unroll
    for (int et = 0; et < 4; ++et) rn_e[et] = s_rn[et * 16 + l15];

    bf16x4 tv[2][4];
    #pragma unroll
    for (int ct = 0; ct < 2; ++ct)
        #pragma unroll
        for (int et = 0; et < 4; ++et) {
            bf16x4 v;
            #pragma unroll
            for (int r = 0; r < 4; ++r)
                v[r] = f2bfr(silu(acc[ct][et][r] + rn_e[et] * w256v[ct][r] + b1v[ct][r]));
            tv[ct][et] = v;
        }
    __syncthreads();   // barrier 2: all MFMA reads of ein done -> t may overlay
    #pragma unroll
    for (int ct = 0; ct < 2; ++ct)
        #pragma unroll
        for (int et = 0; et < 4; ++et)
            *(bf16x4*)&s_u.p.t[et * 16 + l15][n0 + ct * 16 + q * 4] = tv[ct][et];
    __syncthreads();   // barrier 3: t ready

    // ---------------- GEMM2 (swapped): We2 @ t^T -> m ----------------
    f32x4 acc2[2][4] = {};
    __builtin_amdgcn_s_setprio(1);
    #pragma unroll
    for (int ks = 0; ks < 4; ++ks) {
        int k0 = ks * 32 + q * 8;
        bf16x8 w0 = *(const bf16x8*)&W2b[(n0 + l15) * 128 + k0];
        bf16x8 w1 = *(const bf16x8*)&W2b[(n0 + 16 + l15) * 128 + k0];
        bf16x8 e0 = *(const bf16x8*)&s_u.p.t[l15][k0];
        bf16x8 e1 = *(const bf16x8*)&s_u.p.t[16 + l15][k0];
        bf16x8 e2 = *(const bf16x8*)&s_u.p.t[32 + l15][k0];
        bf16x8 e3 = *(const bf16x8*)&s_u.p.t[48 + l15][k0];
        acc2[0][0] = __builtin_amdgcn_mfma_f32_16x16x32_bf16(w0, e0, acc2[0][0], 0, 0, 0);
        acc2[0][1] = __builtin_amdgcn_mfma_f32_16x16x32_bf16(w0, e1, acc2[0][1], 0, 0, 0);
        acc2[0][2] = __builtin_amdgcn_mfma_f32_16x16x32_bf16(w0, e2, acc2[0][2], 0, 0, 0);
        acc2[0][3] = __builtin_amdgcn_mfma_f32_16x16x32_bf16(w0, e3, acc2[0][3], 0, 0, 0);
        acc2[1][0] = __builtin_amdgcn_mfma_f32_16x16x32_bf16(w1, e0, acc2[1][0], 0, 0, 0);
        acc2[1][1] = __builtin_amdgcn_mfma_f32_16x16x32_bf16(w1, e1, acc2[1][1], 0, 0, 0);
        acc2[1][2] = __builtin_amdgcn_mfma_f32_16x16x32_bf16(w1, e2, acc2[1][2], 0, 0, 0);
        acc2[1][3] = __builtin_amdgcn_mfma_f32_16x16x32_bf16(w1, e3, acc2[1][3], 0, 0, 0);
    }
    __builtin_amdgcn_s_setprio(0);

    // epilogue 2 writes m region (disjoint from t region; no barrier needed)
    {
        float b2v[2][4];
        #pragma unroll
        for (int ct = 0; ct < 2; ++ct)
            #pragma unroll
            for (int r = 0; r < 4; ++r)
                b2v[ct][r] = be2[n0 + ct * 16 + q * 4 + r];
        #pragma unroll
        for (int ct = 0; ct < 2; ++ct)
            #pragma unroll
            for (int et = 0; et < 4; ++et) {
                bf16x4 v;
                #pragma unroll
                for (int r = 0; r < 4; ++r)
                    v[r] = f2bfr(acc2[ct][et][r] + b2v[ct][r]);
                *(bf16x4*)&s_u.p.m[et * 16 + l15][n0 + ct * 16 + q * 4] = v;
            }
    }
    __syncthreads();   // barrier 4: m ready

    // ---------------- GEMM3 (swapped): Wc1 @ m^T, dot wc2 ----------------
    f32x4 acc3[2][4] = {};
    __builtin_amdgcn_s_setprio(1);
    #pragma unroll
    for (int ks = 0; ks < 4; ++ks) {
        int k0 = ks * 32 + q * 8;
        bf16x8 w0 = *(const bf16x8*)&Wc1b[(n0 + l15) * 128 + k0];
        bf16x8 w1 = *(const bf16x8*)&Wc1b[(n0 + 16 + l15) * 128 + k0];
        bf16x8 e0 = *(const bf16x8*)&s_u.p.m[l15][k0];
        bf16x8 e1 = *(const bf16x8*)&s_u.p.m[16 + l15][k0];
        bf16x8 e2 = *(const bf16x8*)&s_u.p.m[32 + l15][k0];
        bf16x8 e3 = *(const bf16x8*)&s_u.p.m[48 + l15][k0];
        acc3[0][0] = __builtin_amdgcn_mfma_f32_16x16x32_bf16(w0, e0, acc3[0][0], 0, 0, 0);
        acc3[0][1] = __builtin_amdgcn_mfma_f32_16x16x32_bf16(w0, e1, acc3[0][1], 0, 0, 0);
        acc3[0][2] = __builtin_amdgcn_mfma_f32_16x16x32_bf16(w0, e2, acc3[0][2], 0, 0, 0);
        acc3[0][3] = __builtin_amdgcn_mfma_f32_16x16x32_bf16(w0, e3, acc3[0][3], 0, 0, 0);
        acc3[1][0] = __builtin_amdgcn_mfma_f32_16x16x32_bf16(w1, e0, acc3[1][0], 0, 0, 0);
        acc3[1][1] = __builtin_amdgcn_mfma_f32_16x16x32_bf16(w1, e1, acc3[1][1], 0, 0, 0);
        acc3[1][2] = __builtin_amdgcn_mfma_f32_16x16x32_bf16(w1, e2, acc3[1][2], 0, 0, 0);
        acc3[1][3] = __builtin_amdgcn_mfma_f32_16x16x32_bf16(w1, e3, acc3[1][3], 0, 0, 0);
    }
    __builtin_amdgcn_s_setprio(0);

    // per-lane partial dot over this lane's 8 channels, per edge tile
    float p[4] = {0.f, 0.f, 0.f, 0.f};
    #pragma unroll
    for (int ct = 0; ct < 2; ++ct)
        #pragma unroll
        for (int r = 0; r < 4; ++r) {
            int ch = n0 + ct * 16 + q * 4 + r;
            float bias = bc1[ch];
            float w2   = wc2f[ch];
            #pragma unroll
            for (int et = 0; et < 4; ++et)
                p[et] += silu(acc3[ct][et][r] + bias) * w2;
        }
    #pragma unroll
    for (int et = 0; et < 4; ++et) {
        float v = p[et];
        v += __shfl_xor(v, 16);
        v += __shfl_xor(v, 32);
        if (q == et) atomicAdd(&s_dot[et * 16 + l15], v);  // one LDS atomic / lane
    }
    __syncthreads();   // barrier 5: s_dot complete

    // ---- tail: pos update + agg atomics (fire-and-forget, never drained) ----
    if (tid < EPB) {
        float s = tanhf(s_dot[tid] + bc2[0]) * 0.1f;
        int r = s_row[tid];
        atomicAdd(&pos_out[r * 3 + 0], s * s_unit[tid][0]);
        atomicAdd(&pos_out[r * 3 + 1], s * s_unit[tid][1]);
        atomicAdd(&pos_out[r * 3 + 2], s * s_unit[tid][2]);
    }

    // wave-per-row: all 64 lanes of a wave hit ONE node row, 64 consecutive
    // dwords (256B contiguous). This TCC-coalesced burst is mandatory --
    // a 4-row/16B-stride variant tripled WRITE_SIZE (875MB) and 2.6x'd time.
    if constexpr (AGGBF16) {
        #pragma unroll
        for (int i = 0; i < 16; ++i) {
            int row = w + i * 4;
            unsigned pr = *(const unsigned*)&s_u.p.m[row][lane * 2];
            pk_agg_add(&aggb[(size_t)s_row[row] * 64 + lane], pr);
        }
    } else {
        #pragma unroll
        for (int i = 0; i < 16; ++i) {
            int row = w + i * 4;
            unsigned pr = *(const unsigned*)&s_u.p.m[row][lane * 2];
            float f0 = __builtin_bit_cast(float, pr << 16);
            float f1 = __builtin_bit_cast(float, pr & 0xFFFF0000u);
            float* dst = &aggf[(size_t)s_row[row] * H + 2 * lane];
            atomicAdd(dst, f0);
            atomicAdd(dst + 1, f1);
        }
    }
}

// ---- node kernel: 32 nodes / block ----
template<bool AGGBF16>
__global__ __launch_bounds__(256) void node_kernel(
    const float* __restrict__ h, const short* __restrict__ hbf,
    const unsigned short* __restrict__ aggb, const float* __restrict__ aggf,
    const float* __restrict__ bn1, const float* __restrict__ bn2,
    const short* __restrict__ Wn1b, const short* __restrict__ Wn2b,
    float* __restrict__ hout)
{
    __shared__ short s_a[32][264];
    __shared__ short s_t[32][136];

    const int tid = threadIdx.x;
    const int nb  = blockIdx.x * 32;

    {
        const int rlane = tid & 15;
        const int row0  = tid >> 4;
        #pragma unroll
        for (int it = 0; it < 4; ++it) {
            int rr = row0 + it * 16;     // 0..63
            int e  = rr & 31, sg = rr >> 5;
            int node = nb + e;
            if (node >= N_NODES) node = N_NODES - 1;
            bf16x8 v;
            if (sg == 0) {
                v = *(const bf16x8*)&hbf[(size_t)node * H + rlane * 8];
            } else if constexpr (AGGBF16) {
                v = *(const bf16x8*)&aggb[(size_t)node * H + rlane * 8];
            } else {
                const float* src = &aggf[(size_t)node * H + rlane * 8];
                bf16x8 t;
                #pragma unroll
                for (int j = 0; j < 8; ++j) t[j] = f2bfr(src[j]);
                v = t;
            }
            *(bf16x8*)&s_a[e][sg * 128 + rlane * 8] = v;
        }
    }
    __syncthreads();

    const int lane = tid & 63;
    const int q    = lane >> 4;
    const int l15  = lane & 15;
    const int n0   = (tid >> 6) * 32;

    f32x4 acc[2][2] = {};
    #pragma unroll
    for (int ks = 0; ks < 8; ++ks) {
        int k0 = ks * 32 + q * 8;
        bf16x8 a0 = *(const bf16x8*)&s_a[l15][k0];
        bf16x8 a1 = *(const bf16x8*)&s_a[16 + l15][k0];
        bf16x8 b0 = *(const bf16x8*)&Wn1b[(n0 + l15) * 264 + k0];
        bf16x8 b1 = *(const bf16x8*)&Wn1b[(n0 + 16 + l15) * 264 + k0];
        acc[0][0] = __builtin_amdgcn_mfma_f32_16x16x32_bf16(a0, b0, acc[0][0], 0, 0, 0);
        acc[0][1] = __builtin_amdgcn_mfma_f32_16x16x32_bf16(a0, b1, acc[0][1], 0, 0, 0);
        acc[1][0] = __builtin_amdgcn_mfma_f32_16x16x32_bf16(a1, b0, acc[1][0], 0, 0, 0);
        acc[1][1] = __builtin_amdgcn_mfma_f32_16x16x32_bf16(a1, b1, acc[1][1], 0, 0, 0);
    }
    #pragma unroll
    for (int ct = 0; ct < 2; ++ct) {
        int col = n0 + ct * 16 + l15;
        float bias = bn1[col];
        #pragma unroll
        for (int rt = 0; rt < 2; ++rt) {
            #pragma unroll
            for (int r = 0; r < 4; ++r) {
                int row = rt * 16 + q * 4 + r;
                s_t[row][col] = f2bfr(silu(acc[rt][ct][r] + bias));
            }
        }
    }
    __syncthreads();

    f32x4 acc2[2][2] = {};
    #pragma unroll
    for (int ks = 0; ks < 4; ++ks) {
        int k0 = ks * 32 + q * 8;
        bf16x8 a0 = *(const bf16x8*)&s_t[l15][k0];
        bf16x8 a1 = *(const bf16x8*)&s_t[16 + l15][k0];
        bf16x8 b0 = *(const bf16x8*)&Wn2b[(n0 + l15) * 128 + k0];
        bf16x8 b1 = *(const bf16x8*)&Wn2b[(n0 + 16 + l15) * 128 + k0];
        acc2[0][0] = __builtin_amdgcn_mfma_f32_16x16x32_bf16(a0, b0, acc2[0][0], 0, 0, 0);
        acc2[0][1] = __builtin_amdgcn_mfma_f32_16x16x32_bf16(a0, b1, acc2[0][1], 0, 0, 0);
        acc2[1][0] = __builtin_amdgcn_mfma_f32_16x16x32_bf16(a1, b0, acc2[1][0], 0, 0, 0);
        acc2[1][1] = __builtin_amdgcn_mfma_f32_16x16x32_bf16(a1, b1, acc2[1][1], 0, 0, 0);
    }
    #pragma unroll
    for (int ct = 0; ct < 2; ++ct) {
        int col = n0 + ct * 16 + l15;
        float bias = bn2[col];
        #pragma unroll
        for (int rt = 0; rt < 2; ++rt) {
            #pragma unroll
            for (int r = 0; r < 4; ++r) {
                int row = rt * 16 + q * 4 + r;
                int nrow = nb + row;
                if (nrow < N_NODES) {
                    float v = acc2[rt][ct][r] + bias + h[(size_t)nrow * H + col];
                    hout[(size_t)nrow * H + col] = v;
                }
            }
        }
    }
}

extern "C" void kernel_launch(void* const* d_in, const int* in_sizes, int n_in,
                              void* d_out, int out_size, void* d_ws, size_t ws_size,
                              hipStream_t stream) {
    const float* h   = (const float*)d_in[0];
    const float* pos = (const float*)d_in[1];
    const int*  eidx = (const int*)d_in[2];
    const float* We1 = (const float*)d_in[3];
    const float* be1 = (const float*)d_in[4];
    const float* We2 = (const float*)d_in[5];
    const float* be2 = (const float*)d_in[6];
    const float* Wn1 = (const float*)d_in[7];
    const float* bn1 = (const float*)d_in[8];
    const float* Wn2 = (const float*)d_in[9];
    const float* bn2 = (const float*)d_in[10];
    const float* Wc1 = (const float*)d_in[11];
    const float* bc1 = (const float*)d_in[12];
    const float* Wc2 = (const float*)d_in[13];
    const float* bc2 = (const float*)d_in[14];

    float* out_h   = (float*)d_out;
    float* out_pos = out_h + (size_t)N_NODES * H;

    char* ws = (char*)d_ws;
    short* W1b  = (short*)(ws);
    short* W2b  = (short*)(ws + 2 * P_W1);
    short* Wc1b = (short*)(ws + 2 * (P_W1 + P_W2));
    short* Wn1b = (short*)(ws + 2 * (P_W1 + 2 * P_W2));
    short* Wn2b = (short*)(ws + 2 * (2 * P_W1 + 2 * P_W2));
    const size_t WSW = 2 * (size_t)(2 * P_W1 + 3 * P_W2);   // 233472 B
    const size_t HBF = (size_t)N_NODES * H * 2;             // 12.8 MB
    const size_t AGG = (size_t)N_NODES * H * 2;             // 12.8 MB
    short* hbf = (short*)(ws + WSW);
    const bool use_bf16 = (ws_size >= WSW + HBF + AGG);

    if (use_bf16) {
        unsigned* aggb = (unsigned*)(ws + WSW + HBF);
        const int prep_n = NH4 + P_TOT + AGG16 + POS4;
        prep_all<<<(prep_n + 255) / 256, 256, 0, stream>>>(
            h, We1, We2, Wc1, Wn1, Wn2, hbf, W1b, W2b, Wc1b, Wn1b, Wn2b,
            (uint4*)aggb, AGG16, (float4*)out_pos, (const float4*)pos);
        edge_kernel<true><<<N_EDGES / EPB, 256, 0, stream>>>(
            hbf, pos, eidx, We1, be1, be2, bc1, Wc2, bc2,
            W1b, W2b, Wc1b, aggb, nullptr, out_pos);
        node_kernel<true><<<(N_NODES + 31) / 32, 256, 0, stream>>>(
            h, hbf, (const unsigned short*)aggb, nullptr,
            bn1, bn2, Wn1b, Wn2b, out_h);
    } else {
        // fallback: f32 agg in d_out h region
        const int prep_n = NH4 + P_TOT + POS4;
        prep_all<<<(prep_n + 255) / 256, 256, 0, stream>>>(
            h, We1, We2, Wc1, Wn1, Wn2, hbf, W1b, W2b, Wc1b, Wn1b, Wn2b,
            nullptr, 0, (float4*)out_pos, (const float4*)pos);
        hipMemsetAsync(out_h, 0, (size_t)N_NODES * H * sizeof(float), stream);
        edge_kernel<false><<<N_EDGES / EPB, 256, 0, stream>>>(
            hbf, pos, eidx, We1, be1, be2, bc1, Wc2, bc2,
            W1b, W2b, Wc1b, nullptr, out_h, out_pos);
        node_kernel<false><<<(N_NODES + 31) / 32, 256, 0, stream>>>(
            h, hbf, nullptr, out_h, bn1, bn2, Wn1b, Wn2b, out_h);
    }
}

// Round 3
// 430.921 us; speedup vs baseline: 2.2540x; 1.1558x over previous
//
#include <hip/hip_runtime.h>
#include <math.h>

#define N_NODES 50000
#define N_EDGES 800000
#define H 128
#define EIN 257
#define EPB 64   // edges per block
#define NWG_EDGE (N_EDGES / EPB)     // 12500
#define CNT_PAD 50176                // 196*256
#define NBS 196                      // scan blocks

typedef short bf16x8 __attribute__((ext_vector_type(8)));
typedef short bf16x4 __attribute__((ext_vector_type(4)));
typedef short bf16x2 __attribute__((ext_vector_type(2)));
typedef float f32x4 __attribute__((ext_vector_type(4)));

// round-to-nearest-even f32 -> bf16 (one-time prep conversions)
static __device__ __forceinline__ short f2bf(float x) {
    unsigned u = __builtin_bit_cast(unsigned, x);
    unsigned r = (u + 0x7FFFu + ((u >> 16) & 1u)) >> 16;
    return (short)r;
}

// cheap round-half-up f32 -> bf16 (2 VALU insts)
static __device__ __forceinline__ short f2bfr(float x) {
    return (short)((__builtin_bit_cast(unsigned, x) + 0x8000u) >> 16);
}

// fast silu
static __device__ __forceinline__ float silu(float x) {
#if __has_builtin(__builtin_amdgcn_rcpf)
    return x * __builtin_amdgcn_rcpf(1.0f + __expf(-x));
#else
    return x / (1.0f + __expf(-x));
#endif
}

// packed bf16 atomic add
static __device__ __forceinline__ void pk_agg_add(unsigned* addr, unsigned val) {
#if __has_builtin(__builtin_amdgcn_global_atomic_fadd_v2bf16)
    bf16x2 v = __builtin_bit_cast(bf16x2, val);
    (void)__builtin_amdgcn_global_atomic_fadd_v2bf16(
        (__attribute__((address_space(1))) bf16x2*)(unsigned long long)addr, v);
#else
    asm volatile("global_atomic_pk_add_bf16 %0, %1, off"
                 :: "v"(addr), "v"(val) : "memory");
#endif
}

// ---- prep: h->bf16, weights->bf16 (padded), agg zero, pos copy, row hist ----
#define P_W1  (128*264)
#define P_W2  (128*128)
#define P_TOT (P_W1 + P_W2 + P_W2 + P_W1 + P_W2)
#define NH4   (N_NODES * H / 4)          // h float4 count = 1,600,000
#define AGG16 (N_NODES * H * 2 / 16)     // agg bf16 bytes / 16 = 800,000
#define POS4  ((N_NODES * 3 + 3) / 4)    // pos float4 count (150000/4=37500)

__global__ __launch_bounds__(256) void prep_all(
    const float* __restrict__ hf,
    const float* __restrict__ We1, const float* __restrict__ We2,
    const float* __restrict__ Wc1, const float* __restrict__ Wn1,
    const float* __restrict__ Wn2,
    short* __restrict__ hbf,
    short* __restrict__ W1b, short* __restrict__ W2b, short* __restrict__ Wc1b,
    short* __restrict__ Wn1b, short* __restrict__ Wn2b,
    uint4* __restrict__ aggz, int aggz_n,          // zero-fill region (16B units)
    float4* __restrict__ pos_dst, const float4* __restrict__ pos_src,
    const int* __restrict__ erow, unsigned* __restrict__ cnt)  // row histogram
{
    int i = blockIdx.x * 256 + threadIdx.x;
    if (i < NH4) {
        float4 v = ((const float4*)hf)[i];
        bf16x4 s4 = { f2bf(v.x), f2bf(v.y), f2bf(v.z), f2bf(v.w) };
        *(bf16x4*)&hbf[i * 4] = s4;
        return;
    }
    i -= NH4;
    if (i < P_TOT) {
        if (i < P_W1) {
            int j = i / 264, k = i % 264;
            W1b[i] = (k < EIN) ? f2bf(We1[j * EIN + k]) : (short)0;
        } else if (i < P_W1 + P_W2) {
            int t = i - P_W1;
            W2b[t] = f2bf(We2[t]);
        } else if (i < P_W1 + 2 * P_W2) {
            int t = i - P_W1 - P_W2;
            Wc1b[t] = f2bf(Wc1[t]);
        } else if (i < P_W1 + 2 * P_W2 + P_W1) {
            int t = i - P_W1 - 2 * P_W2;
            int j = t / 264, k = t % 264;
            Wn1b[t] = (k < 256) ? f2bf(Wn1[j * 256 + k]) : (short)0;
        } else {
            int t = i - 2 * P_W1 - 2 * P_W2;
            Wn2b[t] = f2bf(Wn2[t]);
        }
        return;
    }
    i -= P_TOT;
    if (i < aggz_n) {                    // bf16 +0.0 == 0x0000
        aggz[i] = uint4{0u, 0u, 0u, 0u};
        return;
    }
    i -= aggz_n;
    if (i < POS4) { pos_dst[i] = pos_src[i]; return; }
    i -= POS4;
    if (cnt && i < N_EDGES) atomicAdd(&cnt[erow[i]], 1u);
}

// ---- counting-sort support kernels ----
__global__ __launch_bounds__(256) void zero_cnt(unsigned* __restrict__ cnt) {
    int i = blockIdx.x * 256 + threadIdx.x;
    if (i < CNT_PAD) cnt[i] = 0u;
}

// block-local exclusive scan of 256 elements; emits block total
__global__ __launch_bounds__(256) void scan1(const unsigned* __restrict__ cnt,
                                             unsigned* __restrict__ offs,
                                             unsigned* __restrict__ bsum) {
    int t = threadIdx.x;
    int i = blockIdx.x * 256 + t;
    unsigned v = (i < N_NODES) ? cnt[i] : 0u;
    unsigned orig = v;
    #pragma unroll
    for (int d = 1; d < 64; d <<= 1) {
        unsigned n = __shfl_up(v, d);
        if ((t & 63) >= d) v += n;
    }
    __shared__ unsigned wsum[4], woff[4];
    if ((t & 63) == 63) wsum[t >> 6] = v;
    __syncthreads();
    if (t == 0) {
        unsigned r = 0;
        #pragma unroll
        for (int k = 0; k < 4; ++k) { woff[k] = r; r += wsum[k]; }
    }
    __syncthreads();
    unsigned incl = v + woff[t >> 6];
    offs[i] = incl - orig;                 // offs padded to CNT_PAD
    if (t == 255) bsum[blockIdx.x] = incl;
}

__global__ __launch_bounds__(256) void scan2(unsigned* __restrict__ bsum) {
    int t = threadIdx.x;
    unsigned v = (t < NBS) ? bsum[t] : 0u;
    unsigned orig = v;
    #pragma unroll
    for (int d = 1; d < 64; d <<= 1) {
        unsigned n = __shfl_up(v, d);
        if ((t & 63) >= d) v += n;
    }
    __shared__ unsigned wsum[4], woff[4];
    if ((t & 63) == 63) wsum[t >> 6] = v;
    __syncthreads();
    if (t == 0) {
        unsigned r = 0;
        #pragma unroll
        for (int k = 0; k < 4; ++k) { woff[k] = r; r += wsum[k]; }
    }
    __syncthreads();
    unsigned incl = v + woff[t >> 6];
    if (t < NBS) bsum[t] = incl - orig;    // exclusive
}

__global__ __launch_bounds__(256) void scan3(unsigned* __restrict__ offs,
                                             const unsigned* __restrict__ bsum) {
    int i = blockIdx.x * 256 + threadIdx.x;
    offs[i] += bsum[blockIdx.x];
}

__global__ __launch_bounds__(256) void scatter_edges(const int* __restrict__ eidx,
        unsigned* __restrict__ offs, int* __restrict__ rs, int* __restrict__ cs) {
    int e = blockIdx.x * 256 + threadIdx.x;
    if (e < N_EDGES) {
        int r = eidx[e];
        unsigned p = atomicAdd(&offs[r], 1u);
        rs[p] = r;
        cs[p] = eidx[N_EDGES + e];
    }
}

// ---- edge kernel: 64 edges / block, 256 threads (4 waves) ----
// Input edges are SORTED by row (counting sort). Consequences exploited here:
//  - h[row] gather is near-sequential (L1/L2 hits).
//  - agg: per-wave f32 run-accumulation over contiguous equal-row edges, one
//    coalesced 256B packed-bf16 atomic burst per run (~10x fewer atomics).
//  - pos: run-reduced, one f32 atomic triple per run.
//  - chunked bijective XCD swizzle: each XCD covers a contiguous 1/8 of sorted
//    edges -> its agg slice (~1.6MB) is L2-resident -> atomic RMWs hit L2.
// Agg flush sits BEFORE GEMM3 so the atomics overlap MFMA (round-0 lesson:
// end-of-kernel placement loses the overlap; scattered bursts triple WRITE_SIZE).
template<bool AGGBF16>
__global__ __launch_bounds__(256, 4) void edge_kernel(
    const short* __restrict__ hbf, const float* __restrict__ pos,
    const int* __restrict__ rsrc, const int* __restrict__ csrc,
    const float* __restrict__ We1f, const float* __restrict__ be1,
    const float* __restrict__ be2, const float* __restrict__ bc1,
    const float* __restrict__ wc2f, const float* __restrict__ bc2,
    const short* __restrict__ W1b, const short* __restrict__ W2b,
    const short* __restrict__ Wc1b,
    unsigned* __restrict__ aggb,   // bf16 agg, 64 dwords/row
    float* __restrict__ aggf,      // f32 agg (fallback)
    float* __restrict__ pos_out)
{
    __shared__ union {
        short ein[EPB][264];                               // 33792 B (phase A)
        struct { short t[EPB][136]; short m[EPB][136]; } p; // 34816 B (phase B)
    } s_u;
    __shared__ float s_rn[EPB];
    __shared__ float s_unit[EPB][3];
    __shared__ int   s_row[EPB];
    __shared__ float s_dot[EPB];

    const int tid = threadIdx.x;

    // bijective chunked XCD swizzle (NWG_EDGE = 12500, 8 XCDs, m204 formula)
    int wg;
    {
        const int Q = NWG_EDGE >> 3, R = NWG_EDGE & 7;     // 1562, 4
        int x = blockIdx.x & 7, k = blockIdx.x >> 3;
        int start = (x < R) ? x * (Q + 1) : R * (Q + 1) + (x - R) * Q;
        wg = start + k;
    }
    const int eb = wg * EPB;

    if (tid < EPB) {
        int ge = eb + tid;
        int r = rsrc[ge];
        int c = csrc[ge];
        s_row[tid] = r;
        float dx = pos[r*3+0] - pos[c*3+0];
        float dy = pos[r*3+1] - pos[c*3+1];
        float dz = pos[r*3+2] - pos[c*3+2];
        float nrm = sqrtf(dx*dx + dy*dy + dz*dz);
        float rn  = fmaxf(nrm, 1e-8f);
        s_rn[tid] = rn;
        s_unit[tid][0] = dx / rn;
        s_unit[tid][1] = dy / rn;
        s_unit[tid][2] = dz / rn;
        s_dot[tid] = 0.0f;
    }

    // gather hbf[row]|hbf[col] -> s_ein: pure bf16 16B moves.
    {
        const int rlane = tid & 15;
        const int row0  = tid >> 4;      // 0..15
        int idxs[8];
        #pragma unroll
        for (int it = 0; it < 8; ++it) {
            int rr = row0 + it * 16;     // 0..127
            int e  = rr & 63, sg = rr >> 6;
            idxs[it] = (sg ? csrc : rsrc)[eb + e];
        }
        #pragma unroll
        for (int it = 0; it < 8; ++it) {
            int rr = row0 + it * 16;
            int e  = rr & 63, sg = rr >> 6;
            bf16x8 v = *(const bf16x8*)&hbf[(size_t)idxs[it] * H + rlane * 8];
            *(bf16x8*)&s_u.ein[e][sg * 128 + rlane * 8] = v;
        }
    }
    __syncthreads();   // barrier 1: ein ready

    const int lane = tid & 63;
    const int q    = lane >> 4;
    const int l15  = lane & 15;
    const int n0   = (tid >> 6) * 32;    // wave's channel base
    const int w    = tid >> 6;

    // ---------------- GEMM1 (swapped): We1 @ ein^T ----------------
    f32x4 acc[2][4] = {};   // [channel-tile ct][edge-tile et]
    #pragma unroll
    for (int ks = 0; ks < 8; ++ks) {
        int k0 = ks * 32 + q * 8;
        bf16x8 w0 = *(const bf16x8*)&W1b[(n0 + l15) * 264 + k0];
        bf16x8 w1 = *(const bf16x8*)&W1b[(n0 + 16 + l15) * 264 + k0];
        bf16x8 e0 = *(const bf16x8*)&s_u.ein[l15][k0];
        bf16x8 e1 = *(const bf16x8*)&s_u.ein[16 + l15][k0];
        bf16x8 e2 = *(const bf16x8*)&s_u.ein[32 + l15][k0];
        bf16x8 e3 = *(const bf16x8*)&s_u.ein[48 + l15][k0];
        acc[0][0] = __builtin_amdgcn_mfma_f32_16x16x32_bf16(w0, e0, acc[0][0], 0, 0, 0);
        acc[0][1] = __builtin_amdgcn_mfma_f32_16x16x32_bf16(w0, e1, acc[0][1], 0, 0, 0);
        acc[0][2] = __builtin_amdgcn_mfma_f32_16x16x32_bf16(w0, e2, acc[0][2], 0, 0, 0);
        acc[0][3] = __builtin_amdgcn_mfma_f32_16x16x32_bf16(w0, e3, acc[0][3], 0, 0, 0);
        acc[1][0] = __builtin_amdgcn_mfma_f32_16x16x32_bf16(w1, e0, acc[1][0], 0, 0, 0);
        acc[1][1] = __builtin_amdgcn_mfma_f32_16x16x32_bf16(w1, e1, acc[1][1], 0, 0, 0);
        acc[1][2] = __builtin_amdgcn_mfma_f32_16x16x32_bf16(w1, e2, acc[1][2], 0, 0, 0);
        acc[1][3] = __builtin_amdgcn_mfma_f32_16x16x32_bf16(w1, e3, acc[1][3], 0, 0, 0);
    }

    // epilogue 1 into registers (ein still live until barrier 2)
    float w256v[2][4], b1v[2][4], rn_e[4];
    #pragma unroll
    for (int ct = 0; ct < 2; ++ct)
        #pragma unroll
        for (int r = 0; r < 4; ++r) {
            int ch = n0 + ct * 16 + q * 4 + r;
            w256v[ct][r] = We1f[ch * EIN + 256];   // rank-1 fixup for odd K
            b1v[ct][r]   = be1[ch];
        }
    #pragma unroll
    for (int et = 0; et < 4; ++et) rn_e[et] = s_rn[et * 16 + l15];

    bf16x4 tv[2][4];
    #pragma unroll
    for (int ct = 0; ct < 2; ++ct)
        #pragma unroll
        for (int et = 0; et < 4; ++et) {
            bf16x4 v;
            #pragma unroll
            for (int r = 0; r < 4; ++r)
                v[r] = f2bfr(silu(acc[ct][et][r] + rn_e[et] * w256v[ct][r] + b1v[ct][r]));
            tv[ct][et] = v;
        }
    __syncthreads();   // barrier 2: all MFMA reads of ein done -> t may overlay
    #pragma unroll
    for (int ct = 0; ct < 2; ++ct)
        #pragma unroll
        for (int et = 0; et < 4; ++et)
            *(bf16x4*)&s_u.p.t[et * 16 + l15][n0 + ct * 16 + q * 4] = tv[ct][et];
    __syncthreads();   // barrier 3: t ready

    // ---------------- GEMM2 (swapped): We2 @ t^T -> m ----------------
    f32x4 acc2[2][4] = {};
    #pragma unroll
    for (int ks = 0; ks < 4; ++ks) {
        int k0 = ks * 32 + q * 8;
        bf16x8 w0 = *(const bf16x8*)&W2b[(n0 + l15) * 128 + k0];
        bf16x8 w1 = *(const bf16x8*)&W2b[(n0 + 16 + l15) * 128 + k0];
        bf16x8 e0 = *(const bf16x8*)&s_u.p.t[l15][k0];
        bf16x8 e1 = *(const bf16x8*)&s_u.p.t[16 + l15][k0];
        bf16x8 e2 = *(const bf16x8*)&s_u.p.t[32 + l15][k0];
        bf16x8 e3 = *(const bf16x8*)&s_u.p.t[48 + l15][k0];
        acc2[0][0] = __builtin_amdgcn_mfma_f32_16x16x32_bf16(w0, e0, acc2[0][0], 0, 0, 0);
        acc2[0][1] = __builtin_amdgcn_mfma_f32_16x16x32_bf16(w0, e1, acc2[0][1], 0, 0, 0);
        acc2[0][2] = __builtin_amdgcn_mfma_f32_16x16x32_bf16(w0, e2, acc2[0][2], 0, 0, 0);
        acc2[0][3] = __builtin_amdgcn_mfma_f32_16x16x32_bf16(w0, e3, acc2[0][3], 0, 0, 0);
        acc2[1][0] = __builtin_amdgcn_mfma_f32_16x16x32_bf16(w1, e0, acc2[1][0], 0, 0, 0);
        acc2[1][1] = __builtin_amdgcn_mfma_f32_16x16x32_bf16(w1, e1, acc2[1][1], 0, 0, 0);
        acc2[1][2] = __builtin_amdgcn_mfma_f32_16x16x32_bf16(w1, e2, acc2[1][2], 0, 0, 0);
        acc2[1][3] = __builtin_amdgcn_mfma_f32_16x16x32_bf16(w1, e3, acc2[1][3], 0, 0, 0);
    }

    // epilogue 2 writes m region (disjoint from t region; no barrier needed)
    {
        float b2v[2][4];
        #pragma unroll
        for (int ct = 0; ct < 2; ++ct)
            #pragma unroll
            for (int r = 0; r < 4; ++r)
                b2v[ct][r] = be2[n0 + ct * 16 + q * 4 + r];
        #pragma unroll
        for (int ct = 0; ct < 2; ++ct)
            #pragma unroll
            for (int et = 0; et < 4; ++et) {
                bf16x4 v;
                #pragma unroll
                for (int r = 0; r < 4; ++r)
                    v[r] = f2bfr(acc2[ct][et][r] + b2v[ct][r]);
                *(bf16x4*)&s_u.p.m[et * 16 + l15][n0 + ct * 16 + q * 4] = v;
            }
    }
    __syncthreads();   // barrier 4: m ready

    // ---- agg: per-wave run-reduce over contiguous sorted rows, coalesced
    // 256B atomic bursts, issued BEFORE GEMM3 so they overlap the MFMAs. ----
    if constexpr (AGGBF16) {
        const int base = w * 16;              // wave owns rows base..base+15
        float a0 = 0.f, a1 = 0.f;
        int cur = s_row[base];
        #pragma unroll
        for (int i = 0; i < 16; ++i) {
            int nd = s_row[base + i];
            if (nd != cur) {
                unsigned pk = ((unsigned)(unsigned short)f2bfr(a0)) |
                              (((unsigned)(unsigned short)f2bfr(a1)) << 16);
                pk_agg_add(&aggb[(size_t)cur * 64 + lane], pk);
                a0 = 0.f; a1 = 0.f; cur = nd;
            }
            unsigned pr = *(const unsigned*)&s_u.p.m[base + i][lane * 2];
            a0 += __builtin_bit_cast(float, pr << 16);
            a1 += __builtin_bit_cast(float, pr & 0xFFFF0000u);
        }
        unsigned pk = ((unsigned)(unsigned short)f2bfr(a0)) |
                      (((unsigned)(unsigned short)f2bfr(a1)) << 16);
        pk_agg_add(&aggb[(size_t)cur * 64 + lane], pk);
    } else {
        #pragma unroll
        for (int i = 0; i < 16; ++i) {
            int row = w * 16 + i;
            unsigned pr = *(const unsigned*)&s_u.p.m[row][lane * 2];
            float f0 = __builtin_bit_cast(float, pr << 16);
            float f1 = __builtin_bit_cast(float, pr & 0xFFFF0000u);
            float* dst = &aggf[(size_t)s_row[row] * H + 2 * lane];
            atomicAdd(dst, f0);
            atomicAdd(dst + 1, f1);
        }
    }

    // ---------------- GEMM3 (swapped): Wc1 @ m^T, dot wc2 ----------------
    f32x4 acc3[2][4] = {};
    #pragma unroll
    for (int ks = 0; ks < 4; ++ks) {
        int k0 = ks * 32 + q * 8;
        bf16x8 w0 = *(const bf16x8*)&Wc1b[(n0 + l15) * 128 + k0];
        bf16x8 w1 = *(const bf16x8*)&Wc1b[(n0 + 16 + l15) * 128 + k0];
        bf16x8 e0 = *(const bf16x8*)&s_u.p.m[l15][k0];
        bf16x8 e1 = *(const bf16x8*)&s_u.p.m[16 + l15][k0];
        bf16x8 e2 = *(const bf16x8*)&s_u.p.m[32 + l15][k0];
        bf16x8 e3 = *(const bf16x8*)&s_u.p.m[48 + l15][k0];
        acc3[0][0] = __builtin_amdgcn_mfma_f32_16x16x32_bf16(w0, e0, acc3[0][0], 0, 0, 0);
        acc3[0][1] = __builtin_amdgcn_mfma_f32_16x16x32_bf16(w0, e1, acc3[0][1], 0, 0, 0);
        acc3[0][2] = __builtin_amdgcn_mfma_f32_16x16x32_bf16(w0, e2, acc3[0][2], 0, 0, 0);
        acc3[0][3] = __builtin_amdgcn_mfma_f32_16x16x32_bf16(w0, e3, acc3[0][3], 0, 0, 0);
        acc3[1][0] = __builtin_amdgcn_mfma_f32_16x16x32_bf16(w1, e0, acc3[1][0], 0, 0, 0);
        acc3[1][1] = __builtin_amdgcn_mfma_f32_16x16x32_bf16(w1, e1, acc3[1][1], 0, 0, 0);
        acc3[1][2] = __builtin_amdgcn_mfma_f32_16x16x32_bf16(w1, e2, acc3[1][2], 0, 0, 0);
        acc3[1][3] = __builtin_amdgcn_mfma_f32_16x16x32_bf16(w1, e3, acc3[1][3], 0, 0, 0);
    }

    // per-lane partial dot over this lane's 8 channels, per edge tile
    float p[4] = {0.f, 0.f, 0.f, 0.f};
    #pragma unroll
    for (int ct = 0; ct < 2; ++ct)
        #pragma unroll
        for (int r = 0; r < 4; ++r) {
            int ch = n0 + ct * 16 + q * 4 + r;
            float bias = bc1[ch];
            float w2   = wc2f[ch];
            #pragma unroll
            for (int et = 0; et < 4; ++et)
                p[et] += silu(acc3[ct][et][r] + bias) * w2;
        }
    #pragma unroll
    for (int et = 0; et < 4; ++et) {
        float v = p[et];
        v += __shfl_xor(v, 16);
        v += __shfl_xor(v, 32);
        if (q == et) atomicAdd(&s_dot[et * 16 + l15], v);  // one LDS atomic / lane
    }
    __syncthreads();   // barrier 5: s_dot complete

    // ---- pos update: scale unit vectors, then run-reduce (sorted rows) ----
    if (tid < EPB) {
        float s = tanhf(s_dot[tid] + bc2[0]) * 0.1f;
        s_unit[tid][0] *= s;
        s_unit[tid][1] *= s;
        s_unit[tid][2] *= s;
    }
    __syncthreads();   // barrier 6: contribs ready
    if (tid < EPB) {
        int r = s_row[tid];
        bool last = (tid == EPB - 1) || (s_row[tid + 1] != r);
        if (last) {
            float sx = 0.f, sy = 0.f, sz = 0.f;
            for (int j = tid; j >= 0 && s_row[j] == r; --j) {
                sx += s_unit[j][0];
                sy += s_unit[j][1];
                sz += s_unit[j][2];
            }
            atomicAdd(&pos_out[r * 3 + 0], sx);
            atomicAdd(&pos_out[r * 3 + 1], sy);
            atomicAdd(&pos_out[r * 3 + 2], sz);
        }
    }
}

// ---- node kernel: 32 nodes / block ----
template<bool AGGBF16>
__global__ __launch_bounds__(256) void node_kernel(
    const float* __restrict__ h, const short* __restrict__ hbf,
    const unsigned short* __restrict__ aggb, const float* __restrict__ aggf,
    const float* __restrict__ bn1, const float* __restrict__ bn2,
    const short* __restrict__ Wn1b, const short* __restrict__ Wn2b,
    float* __restrict__ hout)
{
    __shared__ short s_a[32][264];
    __shared__ short s_t[32][136];

    const int tid = threadIdx.x;
    const int nb  = blockIdx.x * 32;

    {
        const int rlane = tid & 15;
        const int row0  = tid >> 4;
        #pragma unroll
        for (int it = 0; it < 4; ++it) {
            int rr = row0 + it * 16;     // 0..63
            int e  = rr & 31, sg = rr >> 5;
            int node = nb + e;
            if (node >= N_NODES) node = N_NODES - 1;
            bf16x8 v;
            if (sg == 0) {
                v = *(const bf16x8*)&hbf[(size_t)node * H + rlane * 8];
            } else if constexpr (AGGBF16) {
                v = *(const bf16x8*)&aggb[(size_t)node * H + rlane * 8];
            } else {
                const float* src = &aggf[(size_t)node * H + rlane * 8];
                bf16x8 t;
                #pragma unroll
                for (int j = 0; j < 8; ++j) t[j] = f2bfr(src[j]);
                v = t;
            }
            *(bf16x8*)&s_a[e][sg * 128 + rlane * 8] = v;
        }
    }
    __syncthreads();

    const int lane = tid & 63;
    const int q    = lane >> 4;
    const int l15  = lane & 15;
    const int n0   = (tid >> 6) * 32;

    f32x4 acc[2][2] = {};
    #pragma unroll
    for (int ks = 0; ks < 8; ++ks) {
        int k0 = ks * 32 + q * 8;
        bf16x8 a0 = *(const bf16x8*)&s_a[l15][k0];
        bf16x8 a1 = *(const bf16x8*)&s_a[16 + l15][k0];
        bf16x8 b0 = *(const bf16x8*)&Wn1b[(n0 + l15) * 264 + k0];
        bf16x8 b1 = *(const bf16x8*)&Wn1b[(n0 + 16 + l15) * 264 + k0];
        acc[0][0] = __builtin_amdgcn_mfma_f32_16x16x32_bf16(a0, b0, acc[0][0], 0, 0, 0);
        acc[0][1] = __builtin_amdgcn_mfma_f32_16x16x32_bf16(a0, b1, acc[0][1], 0, 0, 0);
        acc[1][0] = __builtin_amdgcn_mfma_f32_16x16x32_bf16(a1, b0, acc[1][0], 0, 0, 0);
        acc[1][1] = __builtin_amdgcn_mfma_f32_16x16x32_bf16(a1, b1, acc[1][1], 0, 0, 0);
    }
    #pragma unroll
    for (int ct = 0; ct < 2; ++ct) {
        int col = n0 + ct * 16 + l15;
        float bias = bn1[col];
        #pragma unroll
        for (int rt = 0; rt < 2; ++rt) {
            #pragma unroll
            for (int r = 0; r < 4; ++r) {
                int row = rt * 16 + q * 4 + r;
                s_t[row][col] = f2bfr(silu(acc[rt][ct][r] + bias));
            }
        }
    }
    __syncthreads();

    f32x4 acc2[2][2] = {};
    #pragma unroll
    for (int ks = 0; ks < 4; ++ks) {
        int k0 = ks * 32 + q * 8;
        bf16x8 a0 = *(const bf16x8*)&s_t[l15][k0];
        bf16x8 a1 = *(const bf16x8*)&s_t[16 + l15][k0];
        bf16x8 b0 = *(const bf16x8*)&Wn2b[(n0 + l15) * 128 + k0];
        bf16x8 b1 = *(const bf16x8*)&Wn2b[(n0 + 16 + l15) * 128 + k0];
        acc2[0][0] = __builtin_amdgcn_mfma_f32_16x16x32_bf16(a0, b0, acc2[0][0], 0, 0, 0);
        acc2[0][1] = __builtin_amdgcn_mfma_f32_16x16x32_bf16(a0, b1, acc2[0][1], 0, 0, 0);
        acc2[1][0] = __builtin_amdgcn_mfma_f32_16x16x32_bf16(a1, b0, acc2[1][0], 0, 0, 0);
        acc2[1][1] = __builtin_amdgcn_mfma_f32_16x16x32_bf16(a1, b1, acc2[1][1], 0, 0, 0);
    }
    #pragma unroll
    for (int ct = 0; ct < 2; ++ct) {
        int col = n0 + ct * 16 + l15;
        float bias = bn2[col];
        #pragma unroll
        for (int rt = 0; rt < 2; ++rt) {
            #pragma unroll
            for (int r = 0; r < 4; ++r) {
                int row = rt * 16 + q * 4 + r;
                int nrow = nb + row;
                if (nrow < N_NODES) {
                    float v = acc2[rt][ct][r] + bias + h[(size_t)nrow * H + col];
                    hout[(size_t)nrow * H + col] = v;
                }
            }
        }
    }
}

extern "C" void kernel_launch(void* const* d_in, const int* in_sizes, int n_in,
                              void* d_out, int out_size, void* d_ws, size_t ws_size,
                              hipStream_t stream) {
    const float* h   = (const float*)d_in[0];
    const float* pos = (const float*)d_in[1];
    const int*  eidx = (const int*)d_in[2];
    const float* We1 = (const float*)d_in[3];
    const float* be1 = (const float*)d_in[4];
    const float* We2 = (const float*)d_in[5];
    const float* be2 = (const float*)d_in[6];
    const float* Wn1 = (const float*)d_in[7];
    const float* bn1 = (const float*)d_in[8];
    const float* Wn2 = (const float*)d_in[9];
    const float* bn2 = (const float*)d_in[10];
    const float* Wc1 = (const float*)d_in[11];
    const float* bc1 = (const float*)d_in[12];
    const float* Wc2 = (const float*)d_in[13];
    const float* bc2 = (const float*)d_in[14];

    float* out_h   = (float*)d_out;
    float* out_pos = out_h + (size_t)N_NODES * H;

    char* ws = (char*)d_ws;
    short* W1b  = (short*)(ws);
    short* W2b  = (short*)(ws + 2 * P_W1);
    short* Wc1b = (short*)(ws + 2 * (P_W1 + P_W2));
    short* Wn1b = (short*)(ws + 2 * (P_W1 + 2 * P_W2));
    short* Wn2b = (short*)(ws + 2 * (2 * P_W1 + 2 * P_W2));
    const size_t WSW = 2 * (size_t)(2 * P_W1 + 3 * P_W2);   // 233472 B
    const size_t HBF = (size_t)N_NODES * H * 2;             // 12.8 MB
    const size_t AGG = (size_t)N_NODES * H * 2;             // 12.8 MB
    const size_t CNTB = (size_t)CNT_PAD * 4;                // 200704 B
    const size_t BSB  = 256 * 4;
    const size_t RSB  = (size_t)N_EDGES * 4;                // 3.2 MB
    short* hbf = (short*)(ws + WSW);
    const bool use_bf16 = (ws_size >= WSW + HBF + AGG);
    const bool use_sort = (ws_size >= WSW + HBF + AGG + CNTB + BSB + 2 * RSB);

    if (use_bf16) {
        unsigned* aggb = (unsigned*)(ws + WSW + HBF);
        if (use_sort) {
            unsigned* cnt  = (unsigned*)(ws + WSW + HBF + AGG);
            unsigned* bsum = (unsigned*)((char*)cnt + CNTB);
            int* rs = (int*)((char*)bsum + BSB);
            int* cs = (int*)((char*)rs + RSB);

            zero_cnt<<<NBS, 256, 0, stream>>>(cnt);
            const int prep_n = NH4 + P_TOT + AGG16 + POS4 + N_EDGES;
            prep_all<<<(prep_n + 255) / 256, 256, 0, stream>>>(
                h, We1, We2, Wc1, Wn1, Wn2, hbf, W1b, W2b, Wc1b, Wn1b, Wn2b,
                (uint4*)aggb, AGG16, (float4*)out_pos, (const float4*)pos,
                eidx, cnt);
            scan1<<<NBS, 256, 0, stream>>>(cnt, cnt, bsum);
            scan2<<<1, 256, 0, stream>>>(bsum);
            scan3<<<NBS, 256, 0, stream>>>(cnt, bsum);
            scatter_edges<<<(N_EDGES + 255) / 256, 256, 0, stream>>>(eidx, cnt, rs, cs);
            edge_kernel<true><<<NWG_EDGE, 256, 0, stream>>>(
                hbf, pos, rs, cs, We1, be1, be2, bc1, Wc2, bc2,
                W1b, W2b, Wc1b, aggb, nullptr, out_pos);
        } else {
            const int prep_n = NH4 + P_TOT + AGG16 + POS4;
            prep_all<<<(prep_n + 255) / 256, 256, 0, stream>>>(
                h, We1, We2, Wc1, Wn1, Wn2, hbf, W1b, W2b, Wc1b, Wn1b, Wn2b,
                (uint4*)aggb, AGG16, (float4*)out_pos, (const float4*)pos,
                nullptr, nullptr);
            edge_kernel<true><<<NWG_EDGE, 256, 0, stream>>>(
                hbf, pos, eidx, eidx + N_EDGES, We1, be1, be2, bc1, Wc2, bc2,
                W1b, W2b, Wc1b, aggb, nullptr, out_pos);
        }
        node_kernel<true><<<(N_NODES + 31) / 32, 256, 0, stream>>>(
            h, hbf, (const unsigned short*)aggb, nullptr,
            bn1, bn2, Wn1b, Wn2b, out_h);
    } else {
        // fallback: f32 agg in d_out h region
        const int prep_n = NH4 + P_TOT + POS4;
        prep_all<<<(prep_n + 255) / 256, 256, 0, stream>>>(
            h, We1, We2, Wc1, Wn1, Wn2, hbf, W1b, W2b, Wc1b, Wn1b, Wn2b,
            nullptr, 0, (float4*)out_pos, (const float4*)pos,
            nullptr, nullptr);
        hipMemsetAsync(out_h, 0, (size_t)N_NODES * H * sizeof(float), stream);
        edge_kernel<false><<<NWG_EDGE, 256, 0, stream>>>(
            hbf, pos, eidx, eidx + N_EDGES, We1, be1, be2, bc1, Wc2, bc2,
            W1b, W2b, Wc1b, nullptr, out_h, out_pos);
        node_kernel<false><<<(N_NODES + 31) / 32, 256, 0, stream>>>(
            h, hbf, nullptr, out_h, bn1, bn2, Wn1b, Wn2b, out_h);
    }
}